// Round 7
// baseline (263.243 us; speedup 1.0000x reference)
//
#include <hip/hip_runtime.h>
#include <hip/hip_bf16.h>

// Dense FFN: out = relu(x @ w1 + b1) @ w2 + b2
// x  [8192,1024] f32, w1 [1024,4096] f32, b1 [4096] f32,
// w2 [4096,1024] f32, b2 [1024] f32, out [8192,1024] f32.
//
// R7: GEMM2 was grid-capped (N=1024 -> 512 wgs = 2 blocks/CU, Occupancy 20%).
//     New gemm2 kernel with 64x128 tile -> 1024 wgs = 4 blocks/CU (LDS 24 KiB,
//     launch_bounds(256,4)).  Same verified chunk-XOR swizzle relation
//     (chunk ^ (row&7)) on both staging and fragment-read sides; LDS dest
//     stays linear (base + tid*16B) so global_load_lds legality holds.
//     GEMM1 (128x128, 5 blocks/CU capable) and fused prep unchanged from R6.

typedef __bf16 bf16;
typedef __bf16 bf16x4 __attribute__((ext_vector_type(4)));
typedef __bf16 bf16x8 __attribute__((ext_vector_type(8)));
typedef float  f32x4  __attribute__((ext_vector_type(4)));

#define BM 128
#define BN 128
#define BK 64

__device__ __forceinline__ void gload_lds16(const bf16* g, bf16* l) {
    __builtin_amdgcn_global_load_lds(
        (const __attribute__((address_space(1))) unsigned int*)g,
        (__attribute__((address_space(3))) unsigned int*)l,
        16, 0, 0);
}

// ---------------------------------------------------------------------------
// fused prep: [0,8192) cast x->bf16; [8192,9216) w1 transpose;
//             [9216,10240) w2 transpose.  All block-uniform branches.
__device__ __forceinline__ void transpose_tile(
    const float* __restrict__ in, bf16* __restrict__ out,
    int K, int N, int k0, int n0, int t, bf16 (*tile)[72])
{
    const int lr = t >> 4;          // 0..15
    const int lc = (t & 15) << 2;   // 0,4,..60
#pragma unroll
    for (int p = 0; p < 4; ++p) {
        int k = p * 16 + lr;
        float4 v = *(const float4*)(in + (size_t)(k0 + k) * N + n0 + lc);
        tile[lc + 0][k] = (bf16)v.x;
        tile[lc + 1][k] = (bf16)v.y;
        tile[lc + 2][k] = (bf16)v.z;
        tile[lc + 3][k] = (bf16)v.w;
    }
    __syncthreads();

    const int wr = t >> 3;          // 0..31
    const int wc = (t & 7) << 3;    // 0,8,..56
#pragma unroll
    for (int p = 0; p < 2; ++p) {
        int n = p * 32 + wr;
        *(bf16x8*)(out + (size_t)(n0 + n) * K + k0 + wc) =
            *(const bf16x8*)&tile[n][wc];
    }
}

__global__ __launch_bounds__(256) void prep_fused(
    const float* __restrict__ x,  bf16* __restrict__ xb,
    const float* __restrict__ w1, bf16* __restrict__ w1t,
    const float* __restrict__ w2, bf16* __restrict__ w2t)
{
    __shared__ __align__(16) bf16 tile[64][72];
    const int bid = blockIdx.x;
    const int t   = threadIdx.x;

    if (bid < 8192) {
        // cast x -> bf16, 4 f32/thread, exactly 8192*256 threads for 8M elems
        int i = bid * 256 + t;
        float4 v = ((const float4*)x)[i];
        bf16x4 o;
        o.x = (bf16)v.x; o.y = (bf16)v.y; o.z = (bf16)v.z; o.w = (bf16)v.w;
        ((bf16x4*)xb)[i] = o;
    } else if (bid < 9216) {
        // w1 [1024][4096] -> w1t [4096][1024]
        int b = bid - 8192;
        transpose_tile(w1, w1t, 1024, 4096, (b >> 6) * 64, (b & 63) * 64, t, tile);
    } else {
        // w2 [4096][1024] -> w2t [1024][4096]
        int b = bid - 9216;
        transpose_tile(w2, w2t, 4096, 1024, (b >> 4) * 64, (b & 15) * 64, t, tile);
    }
}

// ---------------------------------------------------------------------------
// GEMM1: C[m][n] = relu(sum_k A[m][k]*Bt[n][k] + bias), bf16 out.
// Byte-exact R2/R6 body: 128x128 tile, BK=64, 256 thr, 16x16x32 MFMA,
// chunk-XOR swizzle (measured 0 conflicts, 84.6 us).
template <int FUSE_RELU_BF16>
__global__ __launch_bounds__(256, 3) void gemm_bt(
    const bf16* __restrict__ A, const bf16* __restrict__ Bt,
    const float* __restrict__ bias, void* __restrict__ Cout,
    int M, int N, int K)
{
    __shared__ __align__(16) bf16 As[BM * BK];
    __shared__ __align__(16) bf16 Bs[BN * BK];

    const int tid  = threadIdx.x;
    const int wave = tid >> 6;
    const int lane = tid & 63;

    const int l8  = lane >> 3;           // row within 8-row group
    const int c8  = lane & 7;            // LDS chunk slot
    const int swc = (c8 ^ l8) << 3;      // swizzled global chunk -> elem offset
    const size_t K_ = (size_t)K;

    const bf16* gA[4]; const bf16* gB[4];
    bf16* lA[4]; bf16* lB[4];
#pragma unroll
    for (int g = 0; g < 4; ++g) {
        const int rr = wave * 32 + g * 8 + l8;
        gA[g] = A  + ((size_t)blockIdx.y * BM + rr) * K_ + swc;
        gB[g] = Bt + ((size_t)blockIdx.x * BN + rr) * K_ + swc;
        lA[g] = &As[(wave * 32 + g * 8) * BK] + lane * 8;
        lB[g] = &Bs[(wave * 32 + g * 8) * BK] + lane * 8;
    }

    const int wm   = (wave >> 1) << 6;
    const int wn   = (wave & 1) << 6;
    const int quad = lane >> 4;
    const int r    = lane & 15;
    const int r7   = lane & 7;

    f32x4 acc[4][4] = {};

    for (int k0 = 0; k0 < K; k0 += BK) {
        __syncthreads();
#pragma unroll
        for (int g = 0; g < 4; ++g) {
            gload_lds16(gA[g], lA[g]);
            gload_lds16(gB[g], lB[g]);
            gA[g] += BK; gB[g] += BK;
        }
        __syncthreads();

#pragma unroll
        for (int h = 0; h < 2; ++h) {
            const int ch = ((h * 4 + quad) ^ r7) << 3;   // swizzled chunk offset
            bf16x8 af[4], bfr[4];
#pragma unroll
            for (int i = 0; i < 4; ++i)
                af[i] = *(const bf16x8*)&As[(wm + i * 16 + r) * BK + ch];
#pragma unroll
            for (int j = 0; j < 4; ++j)
                bfr[j] = *(const bf16x8*)&Bs[(wn + j * 16 + r) * BK + ch];
#pragma unroll
            for (int i = 0; i < 4; ++i)
#pragma unroll
                for (int j = 0; j < 4; ++j)
                    acc[i][j] = __builtin_amdgcn_mfma_f32_16x16x32_bf16(
                        af[i], bfr[j], acc[i][j], 0, 0, 0);
        }
    }

    const int m_base = blockIdx.y * BM + wm + quad * 4;
    const int n_base = blockIdx.x * BN + wn + r;
    float bv[4];
#pragma unroll
    for (int j = 0; j < 4; ++j) bv[j] = bias[n_base + j * 16];

    if (FUSE_RELU_BF16) {
        bf16* Cb = (bf16*)Cout;
#pragma unroll
        for (int i = 0; i < 4; ++i) {
#pragma unroll
            for (int p = 0; p < 4; ++p) {
                size_t row = (size_t)(m_base + i * 16 + p) * (size_t)N;
#pragma unroll
                for (int j = 0; j < 4; ++j) {
                    float v = acc[i][j][p] + bv[j];
                    v = v > 0.f ? v : 0.f;
                    Cb[row + n_base + j * 16] = (bf16)v;
                }
            }
        }
    } else {
        float* Cf = (float*)Cout;
#pragma unroll
        for (int i = 0; i < 4; ++i) {
#pragma unroll
            for (int p = 0; p < 4; ++p) {
                size_t row = (size_t)(m_base + i * 16 + p) * (size_t)N;
#pragma unroll
                for (int j = 0; j < 4; ++j) {
                    Cf[row + n_base + j * 16] = acc[i][j][p] + bv[j];
                }
            }
        }
    }
}

// ---------------------------------------------------------------------------
// GEMM2: out = h @ w2t^T + b2, f32 out.  64x128 tile, BK=64, 256 thr =
// 4 waves (2M x 2N), per-wave 32x64.  Grid (8,128) = 1024 wgs = 4 blocks/CU
// (was 512 = 2/CU at 128x128 -- the measured 20% occupancy cap).
// LDS 24 KiB.  Staging: round = 256 thr x 16B = 32 rows; A 2 rounds,
// B 4 rounds.  Same chunk-XOR relation: global chunk = slot ^ (row&7);
// LDS dest = base + tid*16B (linear, gload_lds-legal).
__global__ __launch_bounds__(256, 4) void gemm_bt_m64(
    const bf16* __restrict__ A, const bf16* __restrict__ Bt,
    const float* __restrict__ bias, float* __restrict__ Cf,
    int M, int N, int K)
{
    __shared__ __align__(16) bf16 As[64 * BK];    //  8 KiB
    __shared__ __align__(16) bf16 Bs[128 * BK];   // 16 KiB

    const int tid  = threadIdx.x;
    const int wave = tid >> 6;
    const int lane = tid & 63;

    // staging: round covers rows (g*32 + tid>>3), chunk slot tid&7
    const int r32  = tid >> 3;                    // 0..31 row within round
    const int swcT = ((tid & 7) ^ (r32 & 7)) << 3; // swizzled global chunk
    const size_t K_ = (size_t)K;

    const bf16* gA[2]; const bf16* gB[4];
    bf16* lA[2]; bf16* lB[4];
#pragma unroll
    for (int g = 0; g < 2; ++g) {
        gA[g] = A + ((size_t)blockIdx.y * 64 + g * 32 + r32) * K_ + swcT;
        lA[g] = &As[g * 2048] + tid * 8;          // = (g*32+r32)*64 + (tid&7)*8
    }
#pragma unroll
    for (int g = 0; g < 4; ++g) {
        gB[g] = Bt + ((size_t)blockIdx.x * 128 + g * 32 + r32) * K_ + swcT;
        lB[g] = &Bs[g * 2048] + tid * 8;
    }

    const int wm   = (wave >> 1) << 5;   // 0,32
    const int wn   = (wave & 1) << 6;    // 0,64
    const int quad = lane >> 4;
    const int r    = lane & 15;
    const int r7   = lane & 7;

    f32x4 acc[2][4] = {};

    for (int k0 = 0; k0 < K; k0 += BK) {
        __syncthreads();
#pragma unroll
        for (int g = 0; g < 2; ++g) { gload_lds16(gA[g], lA[g]); gA[g] += BK; }
#pragma unroll
        for (int g = 0; g < 4; ++g) { gload_lds16(gB[g], lB[g]); gB[g] += BK; }
        __syncthreads();

#pragma unroll
        for (int h = 0; h < 2; ++h) {
            const int ch = ((h * 4 + quad) ^ r7) << 3;
            bf16x8 af[2], bfr[4];
#pragma unroll
            for (int i = 0; i < 2; ++i)
                af[i] = *(const bf16x8*)&As[(wm + i * 16 + r) * BK + ch];
#pragma unroll
            for (int j = 0; j < 4; ++j)
                bfr[j] = *(const bf16x8*)&Bs[(wn + j * 16 + r) * BK + ch];
#pragma unroll
            for (int i = 0; i < 2; ++i)
#pragma unroll
                for (int j = 0; j < 4; ++j)
                    acc[i][j] = __builtin_amdgcn_mfma_f32_16x16x32_bf16(
                        af[i], bfr[j], acc[i][j], 0, 0, 0);
        }
    }

    const int m_base = blockIdx.y * 64 + wm + quad * 4;
    const int n_base = blockIdx.x * 128 + wn + r;
    float bv[4];
#pragma unroll
    for (int j = 0; j < 4; ++j) bv[j] = bias[n_base + j * 16];

#pragma unroll
    for (int i = 0; i < 2; ++i) {
#pragma unroll
        for (int p = 0; p < 4; ++p) {
            size_t row = (size_t)(m_base + i * 16 + p) * (size_t)N;
#pragma unroll
            for (int j = 0; j < 4; ++j) {
                Cf[row + n_base + j * 16] = acc[i][j][p] + bv[j];
            }
        }
    }
}

// ---------------------------------------------------------------------------
extern "C" void kernel_launch(void* const* d_in, const int* in_sizes, int n_in,
                              void* d_out, int out_size, void* d_ws, size_t ws_size,
                              hipStream_t stream)
{
    const float* x  = (const float*)d_in[0];  // [8192,1024]
    const float* w1 = (const float*)d_in[1];  // [1024,4096]
    const float* b1 = (const float*)d_in[2];  // [4096]
    const float* w2 = (const float*)d_in[3];  // [4096,1024]
    const float* b2 = (const float*)d_in[4];  // [1024]
    float* out = (float*)d_out;               // [8192,1024]

    const int M = 8192, D = 1024, W = 4096;

    char* ws = (char*)d_ws;
    bf16* xb  = (bf16*)(ws);                           // 16 MiB: [8192,1024]
    bf16* w1t = (bf16*)(ws + (size_t)(16 << 20));      //  8 MiB: [4096,1024]
    bf16* w2t = (bf16*)(ws + (size_t)(24 << 20));      //  8 MiB: [1024,4096]
    bf16* h   = (bf16*)(ws + (size_t)(32 << 20));      // 64 MiB: [8192,4096]

    // 1. fused prep: cast x + transpose w1 + transpose w2 (one launch)
    prep_fused<<<10240, 256, 0, stream>>>(x, xb, w1, w1t, w2, w2t);

    // 2. h = relu(xb @ w1 + b1), bf16  [M][W]   128x128 tile, 2048 wgs
    gemm_bt<1><<<dim3(W / BN, M / BM), 256, 0, stream>>>(
        xb, w1t, b1, (void*)h, M, W, D);

    // 3. out = h @ w2 + b2, f32  [M][D]         64x128 tile, 1024 wgs = 4/CU
    gemm_bt_m64<<<dim3(D / 128, M / 64), 256, 0, stream>>>(
        h, w2t, b2, out, M, D, W);
}

// Round 9
// 248.345 us; speedup vs baseline: 1.0600x; 1.0600x over previous
//
#include <hip/hip_runtime.h>
#include <hip/hip_bf16.h>

// Dense FFN: out = relu(x @ w1 + b1) @ w2 + b2
// x  [8192,1024] f32, w1 [1024,4096] f32, b1 [4096] f32,
// w2 [4096,1024] f32, b2 [1024] f32, out [8192,1024] f32.
//
// R8 (resubmit after container failure): GEMM2 gets BK=128 at 128x128:
//     halves K-iterations (64->32) so half the per-iter barrier+vmcnt(0)
//     drains, at unchanged occupancy (2 blocks/CU grid-pinned; LDS 64 KiB
//     also allows exactly 2).  m132's BK=128 regression was an occupancy
//     drop 3->2; GEMM2 has no such drop.
//     Swizzle generalized to 16 chunks with mask &15: one ds_read's 64 lanes
//     cover 16 consecutive rows (all distinct mod 16) x 4 quads; physical
//     chunk = logical ^ (row&15) -> 16 distinct chunks per quad-group ->
//     uniform bank coverage.  R5's 8.4M-conflict failure is explained by the
//     same rule (rows spanned 32, mask was &7).  Staging: linear LDS dest,
//     inverse-permuted global source (both-sides rule).
//     GEMM1 and fused prep byte-identical to R6 (verified 85 us / 0 confl).

typedef __bf16 bf16;
typedef __bf16 bf16x4 __attribute__((ext_vector_type(4)));
typedef __bf16 bf16x8 __attribute__((ext_vector_type(8)));
typedef float  f32x4  __attribute__((ext_vector_type(4)));

#define BM 128
#define BN 128
#define BK 64

__device__ __forceinline__ void gload_lds16(const bf16* g, bf16* l) {
    __builtin_amdgcn_global_load_lds(
        (const __attribute__((address_space(1))) unsigned int*)g,
        (__attribute__((address_space(3))) unsigned int*)l,
        16, 0, 0);
}

// ---------------------------------------------------------------------------
// fused prep: [0,8192) cast x->bf16; [8192,9216) w1 transpose;
//             [9216,10240) w2 transpose.  All block-uniform branches.
__device__ __forceinline__ void transpose_tile(
    const float* __restrict__ in, bf16* __restrict__ out,
    int K, int N, int k0, int n0, int t, bf16 (*tile)[72])
{
    const int lr = t >> 4;          // 0..15
    const int lc = (t & 15) << 2;   // 0,4,..60
#pragma unroll
    for (int p = 0; p < 4; ++p) {
        int k = p * 16 + lr;
        float4 v = *(const float4*)(in + (size_t)(k0 + k) * N + n0 + lc);
        tile[lc + 0][k] = (bf16)v.x;
        tile[lc + 1][k] = (bf16)v.y;
        tile[lc + 2][k] = (bf16)v.z;
        tile[lc + 3][k] = (bf16)v.w;
    }
    __syncthreads();

    const int wr = t >> 3;          // 0..31
    const int wc = (t & 7) << 3;    // 0,8,..56
#pragma unroll
    for (int p = 0; p < 2; ++p) {
        int n = p * 32 + wr;
        *(bf16x8*)(out + (size_t)(n0 + n) * K + k0 + wc) =
            *(const bf16x8*)&tile[n][wc];
    }
}

__global__ __launch_bounds__(256) void prep_fused(
    const float* __restrict__ x,  bf16* __restrict__ xb,
    const float* __restrict__ w1, bf16* __restrict__ w1t,
    const float* __restrict__ w2, bf16* __restrict__ w2t)
{
    __shared__ __align__(16) bf16 tile[64][72];
    const int bid = blockIdx.x;
    const int t   = threadIdx.x;

    if (bid < 8192) {
        int i = bid * 256 + t;
        float4 v = ((const float4*)x)[i];
        bf16x4 o;
        o.x = (bf16)v.x; o.y = (bf16)v.y; o.z = (bf16)v.z; o.w = (bf16)v.w;
        ((bf16x4*)xb)[i] = o;
    } else if (bid < 9216) {
        int b = bid - 8192;
        transpose_tile(w1, w1t, 1024, 4096, (b >> 6) * 64, (b & 63) * 64, t, tile);
    } else {
        int b = bid - 9216;
        transpose_tile(w2, w2t, 4096, 1024, (b >> 4) * 64, (b & 15) * 64, t, tile);
    }
}

// ---------------------------------------------------------------------------
// GEMM1: C = relu(A @ Bt^T + bias), bf16 out.  Byte-exact R2/R6 body:
// 128x128, BK=64, 256 thr, 16x16x32 MFMA, chunk-XOR swizzle (&7 over 8
// chunks, rows span 16 -> 2 readers/chunk-stripe; measured 0 conflicts).
template <int FUSE_RELU_BF16>
__global__ __launch_bounds__(256, 3) void gemm_bt(
    const bf16* __restrict__ A, const bf16* __restrict__ Bt,
    const float* __restrict__ bias, void* __restrict__ Cout,
    int M, int N, int K)
{
    __shared__ __align__(16) bf16 As[BM * BK];
    __shared__ __align__(16) bf16 Bs[BN * BK];

    const int tid  = threadIdx.x;
    const int wave = tid >> 6;
    const int lane = tid & 63;

    const int l8  = lane >> 3;
    const int c8  = lane & 7;
    const int swc = (c8 ^ l8) << 3;
    const size_t K_ = (size_t)K;

    const bf16* gA[4]; const bf16* gB[4];
    bf16* lA[4]; bf16* lB[4];
#pragma unroll
    for (int g = 0; g < 4; ++g) {
        const int rr = wave * 32 + g * 8 + l8;
        gA[g] = A  + ((size_t)blockIdx.y * BM + rr) * K_ + swc;
        gB[g] = Bt + ((size_t)blockIdx.x * BN + rr) * K_ + swc;
        lA[g] = &As[(wave * 32 + g * 8) * BK] + lane * 8;
        lB[g] = &Bs[(wave * 32 + g * 8) * BK] + lane * 8;
    }

    const int wm   = (wave >> 1) << 6;
    const int wn   = (wave & 1) << 6;
    const int quad = lane >> 4;
    const int r    = lane & 15;
    const int r7   = lane & 7;

    f32x4 acc[4][4] = {};

    for (int k0 = 0; k0 < K; k0 += BK) {
        __syncthreads();
#pragma unroll
        for (int g = 0; g < 4; ++g) {
            gload_lds16(gA[g], lA[g]);
            gload_lds16(gB[g], lB[g]);
            gA[g] += BK; gB[g] += BK;
        }
        __syncthreads();

#pragma unroll
        for (int h = 0; h < 2; ++h) {
            const int ch = ((h * 4 + quad) ^ r7) << 3;
            bf16x8 af[4], bfr[4];
#pragma unroll
            for (int i = 0; i < 4; ++i)
                af[i] = *(const bf16x8*)&As[(wm + i * 16 + r) * BK + ch];
#pragma unroll
            for (int j = 0; j < 4; ++j)
                bfr[j] = *(const bf16x8*)&Bs[(wn + j * 16 + r) * BK + ch];
#pragma unroll
            for (int i = 0; i < 4; ++i)
#pragma unroll
                for (int j = 0; j < 4; ++j)
                    acc[i][j] = __builtin_amdgcn_mfma_f32_16x16x32_bf16(
                        af[i], bfr[j], acc[i][j], 0, 0, 0);
        }
    }

    const int m_base = blockIdx.y * BM + wm + quad * 4;
    const int n_base = blockIdx.x * BN + wn + r;
    float bv[4];
#pragma unroll
    for (int j = 0; j < 4; ++j) bv[j] = bias[n_base + j * 16];

    if (FUSE_RELU_BF16) {
        bf16* Cb = (bf16*)Cout;
#pragma unroll
        for (int i = 0; i < 4; ++i) {
#pragma unroll
            for (int p = 0; p < 4; ++p) {
                size_t row = (size_t)(m_base + i * 16 + p) * (size_t)N;
#pragma unroll
                for (int j = 0; j < 4; ++j) {
                    float v = acc[i][j][p] + bv[j];
                    v = v > 0.f ? v : 0.f;
                    Cb[row + n_base + j * 16] = (bf16)v;
                }
            }
        }
    } else {
        float* Cf = (float*)Cout;
#pragma unroll
        for (int i = 0; i < 4; ++i) {
#pragma unroll
            for (int p = 0; p < 4; ++p) {
                size_t row = (size_t)(m_base + i * 16 + p) * (size_t)N;
#pragma unroll
                for (int j = 0; j < 4; ++j) {
                    Cf[row + n_base + j * 16] = acc[i][j][p] + bv[j];
                }
            }
        }
    }
}

// ---------------------------------------------------------------------------
// GEMM2: out = A @ Bt^T + bias, f32 out.  128x128 tile, BK=128, 256 thr.
// 32 K-iterations (half of BK=64) -> half the barrier/vmcnt(0) drains.
// LDS 64 KiB -> 2 blocks/CU (= the grid-pinned occupancy; no loss).
// Row = 128 elems = 16 chunks of 16B.  Physical chunk = logical ^ (row&15).
// One ds_read: rows span 16 consecutive (all distinct mod 16) -> per
// quad-group 16 distinct chunks -> uniform bank coverage.
// Staging round = 256 thr x 16B = 16 rows; 8 rounds each for A and B.
__global__ __launch_bounds__(256, 2) void gemm_bt2_k128(
    const bf16* __restrict__ A, const bf16* __restrict__ Bt,
    const float* __restrict__ bias, float* __restrict__ Cf,
    int M, int N, int K)
{
    __shared__ __align__(16) bf16 As[128 * 128];   // 32 KiB
    __shared__ __align__(16) bf16 Bs[128 * 128];   // 32 KiB

    const int tid  = threadIdx.x;
    const int wave = tid >> 6;
    const int lane = tid & 63;

    // staging: row-within-round = tid>>4 (16 rows), chunk slot = tid&15.
    // global chunk = slot ^ (row&15)  (involution; linear LDS dest).
    const int sr   = tid >> 4;                     // 0..15
    const int swc  = ((tid & 15) ^ sr) << 3;       // elem offset of 16B chunk
    const size_t K_ = (size_t)K;

    const bf16* gA[8]; const bf16* gB[8];
    bf16* lA[8]; bf16* lB[8];
#pragma unroll
    for (int g = 0; g < 8; ++g) {
        const int rr = g * 16 + sr;
        gA[g] = A  + ((size_t)blockIdx.y * 128 + rr) * K_ + swc;
        gB[g] = Bt + ((size_t)blockIdx.x * 128 + rr) * K_ + swc;
        lA[g] = &As[(g * 16) * 128] + tid * 8;     // linear dest
        lB[g] = &Bs[(g * 16) * 128] + tid * 8;
    }

    const int wm   = (wave >> 1) << 6;
    const int wn   = (wave & 1) << 6;
    const int quad = lane >> 4;
    const int r    = lane & 15;

    f32x4 acc[4][4] = {};

    for (int k0 = 0; k0 < K; k0 += 128) {
        __syncthreads();
#pragma unroll
        for (int g = 0; g < 8; ++g) {
            gload_lds16(gA[g], lA[g]);
            gload_lds16(gB[g], lB[g]);
            gA[g] += 128; gB[g] += 128;
        }
        __syncthreads();

#pragma unroll
        for (int ks = 0; ks < 4; ++ks) {           // 4 k-sub-steps of 32
            bf16x8 af[4], bfr[4];
#pragma unroll
            for (int i = 0; i < 4; ++i) {
                const int row = wm + i * 16 + r;
                const int ch  = (((ks * 4 + quad) ^ (row & 15)) << 3);
                af[i] = *(const bf16x8*)&As[row * 128 + ch];
            }
#pragma unroll
            for (int j = 0; j < 4; ++j) {
                const int row = wn + j * 16 + r;
                const int ch  = (((ks * 4 + quad) ^ (row & 15)) << 3);
                bfr[j] = *(const bf16x8*)&Bs[row * 128 + ch];
            }
#pragma unroll
            for (int i = 0; i < 4; ++i)
#pragma unroll
                for (int j = 0; j < 4; ++j)
                    acc[i][j] = __builtin_amdgcn_mfma_f32_16x16x32_bf16(
                        af[i], bfr[j], acc[i][j], 0, 0, 0);
        }
    }

    const int m_base = blockIdx.y * 128 + wm + quad * 4;
    const int n_base = blockIdx.x * 128 + wn + r;
    float bv[4];
#pragma unroll
    for (int j = 0; j < 4; ++j) bv[j] = bias[n_base + j * 16];

#pragma unroll
    for (int i = 0; i < 4; ++i) {
#pragma unroll
        for (int p = 0; p < 4; ++p) {
            size_t row = (size_t)(m_base + i * 16 + p) * (size_t)N;
#pragma unroll
            for (int j = 0; j < 4; ++j) {
                Cf[row + n_base + j * 16] = acc[i][j][p] + bv[j];
            }
        }
    }
}

// ---------------------------------------------------------------------------
extern "C" void kernel_launch(void* const* d_in, const int* in_sizes, int n_in,
                              void* d_out, int out_size, void* d_ws, size_t ws_size,
                              hipStream_t stream)
{
    const float* x  = (const float*)d_in[0];  // [8192,1024]
    const float* w1 = (const float*)d_in[1];  // [1024,4096]
    const float* b1 = (const float*)d_in[2];  // [4096]
    const float* w2 = (const float*)d_in[3];  // [4096,1024]
    const float* b2 = (const float*)d_in[4];  // [1024]
    float* out = (float*)d_out;               // [8192,1024]

    const int M = 8192, D = 1024, W = 4096;

    char* ws = (char*)d_ws;
    bf16* xb  = (bf16*)(ws);                           // 16 MiB: [8192,1024]
    bf16* w1t = (bf16*)(ws + (size_t)(16 << 20));      //  8 MiB: [4096,1024]
    bf16* w2t = (bf16*)(ws + (size_t)(24 << 20));      //  8 MiB: [1024,4096]
    bf16* h   = (bf16*)(ws + (size_t)(32 << 20));      // 64 MiB: [8192,4096]

    // 1. fused prep: cast x + transpose w1 + transpose w2 (one launch)
    prep_fused<<<10240, 256, 0, stream>>>(x, xb, w1, w1t, w2, w2t);

    // 2. h = relu(xb @ w1 + b1), bf16  [M][W]   128x128 tile, BK=64
    gemm_bt<1><<<dim3(W / BN, M / BM), 256, 0, stream>>>(
        xb, w1t, b1, (void*)h, M, W, D);

    // 3. out = h @ w2 + b2, f32  [M][D]         128x128 tile, BK=128
    gemm_bt2_k128<<<dim3(D / 128, M / 128), 256, 0, stream>>>(
        h, w2t, b2, out, M, D, W);
}